// Round 4
// baseline (304.247 us; speedup 1.0000x reference)
//
#include <hip/hip_runtime.h>

// get_fc_pix_discriminator_1x1_solo: fused 5-layer per-pixel MLP + BCE mean.
// B=4, C=19, H=256, W=512 -> 524288 px. dims 19->64->128->256->512->1.
// R4: fully register-resident activations. Each wave owns 64 px (4 col-blocks
// of 16); weights are the MFMA A-operand streamed from L2 in fragment order;
// activations are the B-operand and STAY IN REGISTERS across all 5 layers.
// The D-layout (col=lane&15=px, row=4g+r=feat) feeds the next layer's B-frag
// (col=px, k=8g+j) directly because the next layer's weight k-dim is permuted
// by sigma(f)=32(f>>5)+8((f>>2)&3)+4((f>>4)&1)+(f&3) in the wconv prepass.
// Bias enters as the MFMA C operand (free). No LDS tiles, no bank conflicts,
// no data barriers (3 alignment-only syncthreads keep waves on the same
// weight stream so L1 dedups the 348KB/wave weight traffic).

#define HW_ 131072      // 256*512 = 2^17
#define NPIX 524288

using bf16x8 = __attribute__((ext_vector_type(8))) short;
using f32x4  = __attribute__((ext_vector_type(4))) float;

#define MFMA __builtin_amdgcn_mfma_f32_16x16x32_bf16

__device__ __forceinline__ unsigned short f2bf(float f) {
  unsigned u = __builtin_bit_cast(unsigned, f);
  u += 0x7FFFu + ((u >> 16) & 1u);   // round-to-nearest-even
  return (unsigned short)(u >> 16);
}

// sigma^-1: k-slot -> source feature index (within 32-chunks)
__device__ __forceinline__ int kinv(int k) {
  return ((k >> 5) << 5) + (((k >> 2) & 1) << 4) + (((k >> 3) & 3) << 2) + (k & 3);
}

// ---- weight bf16 pre-conversion into MFMA A-fragment order ----------------
// layer frag space: [ob = out-block 0..N/16)][ks = 0..KP/32)][lane][j 0..8)
//   o = ob*16 + (lane&15),  k = ks*32 + (lane>>4)*8 + j,
//   feature f = PERM ? kinv(k) : k   (zero if f >= K0)
// elem offset = ((ob*KS+ks)<<9) + lane*8. One wave A-frag load = 1KB coalesced.
#define OW1 0
#define OW2 2048
#define OW3 10240
#define OW4 43008
#define WTOT 174080

template <int K0, int KP, bool PERM>
__device__ __forceinline__ void conv_layer(const float* __restrict__ W,
                                           unsigned short* __restrict__ out,
                                           int i) {
  int r9 = i & 511;
  int lane = r9 >> 3, j = r9 & 7;
  int frag = i >> 9;               // = ob*KS + ks
  constexpr int KS = KP / 32;
  int ob = frag / KS, ks = frag - ob * KS;
  int o = ob * 16 + (lane & 15);
  int k = ks * 32 + ((lane >> 4) << 3) + j;
  int f = PERM ? kinv(k) : k;
  out[i] = f2bf(f < K0 ? W[o * K0 + f] : 0.f);
}

__global__ void wconv_kernel(const float* __restrict__ W1, const float* __restrict__ W2,
                             const float* __restrict__ W3, const float* __restrict__ W4,
                             unsigned short* __restrict__ wb) {
  int i = blockIdx.x * 256 + threadIdx.x;
  if (i < OW2) {
    conv_layer<19, 32, false>(W1, wb + OW1, i - OW1);
  } else if (i < OW3) {
    conv_layer<64, 64, true>(W2, wb + OW2, i - OW2);
  } else if (i < OW4) {
    conv_layer<128, 128, true>(W3, wb + OW3, i - OW3);
  } else if (i < WTOT) {
    conv_layer<256, 256, true>(W4, wb + OW4, i - OW4);
  }
}

__device__ __forceinline__ f32x4 leaky4(f32x4 v) {
  f32x4 r;
#pragma unroll
  for (int i = 0; i < 4; i++) r[i] = fmaxf(v[i], 0.2f * v[i]);
  return r;
}
__device__ __forceinline__ bf16x8 pack8(f32x4 e, f32x4 o) {
  bf16x8 r;
#pragma unroll
  for (int i = 0; i < 4; i++) {
    r[i] = (short)f2bf(e[i]);
    r[4 + i] = (short)f2bf(o[i]);
  }
  return r;
}

// A-frag load: PRE -> 16B vector load from frag-ordered wb; else scalar gather
#define LDA(dst, wbase, Wf, K0, KS, PERM, ob, ks)                              \
  do {                                                                         \
    if constexpr (PRE) {                                                       \
      dst = *(const bf16x8*)((wbase) + ((((ob) * (KS) + (ks)) << 9) + (lane << 3))); \
    } else {                                                                   \
      int o_ = (ob) * 16 + li;                                                 \
      for (int j_ = 0; j_ < 8; j_++) {                                         \
        int k_ = (ks) * 32 + (g << 3) + j_;                                    \
        int f_ = (PERM) ? kinv(k_) : k_;                                       \
        float v_ = f_ < (K0) ? (Wf)[o_ * (K0) + f_] : 0.f;                     \
        dst[j_] = (short)f2bf(v_);                                             \
      }                                                                        \
    }                                                                          \
  } while (0)

template <bool PRE>
__global__ __launch_bounds__(256, 2) void disc_main(
    const float* __restrict__ x, const float* __restrict__ lbl,
    const unsigned short* __restrict__ wb,
    const float* __restrict__ W1f, const float* __restrict__ b1,
    const float* __restrict__ W2f, const float* __restrict__ b2,
    const float* __restrict__ W3f, const float* __restrict__ b3,
    const float* __restrict__ W4f, const float* __restrict__ b4,
    const float* __restrict__ W5f, const float* __restrict__ b5,
    float* __restrict__ out) {
  __shared__ float zs[4];

  int t = threadIdx.x;
  int wave = t >> 6, lane = t & 63;
  int g = lane >> 4, li = lane & 15;
  long px0 = ((long)blockIdx.x * 4 + wave) * 64;
  int b = (int)(px0 >> 17);
  int hw0 = (int)(px0 & (HW_ - 1));

  // ---- x -> B-frags (k = input channel c, natural order; c>=19 zero) ------
  bf16x8 xb[4];
#pragma unroll
  for (int pb = 0; pb < 4; pb++) {
    const float* xp = x + (((long)b * 19) << 17) + hw0 + pb * 16 + li;
    bf16x8 v;
#pragma unroll
    for (int j = 0; j < 8; j++) {
      int c = 8 * g + j;
      float f = (c < 19) ? xp[(long)c << 17] : 0.f;
      v[j] = (short)f2bf(f);
    }
    xb[pb] = v;
  }

  // ---- L1: 19->64 (KS=1, 4 obs) -------------------------------------------
  const unsigned short* w1b = wb + OW1;
  bf16x8 h1[4][2];
#pragma unroll
  for (int obp = 0; obp < 2; obp++) {
    bf16x8 fE, fO;
    LDA(fE, w1b, W1f, 19, 1, false, 2 * obp, 0);
    LDA(fO, w1b, W1f, 19, 1, false, 2 * obp + 1, 0);
    f32x4 bE = *(const f32x4*)(b1 + 32 * obp + 4 * g);
    f32x4 bO = *(const f32x4*)(b1 + 32 * obp + 16 + 4 * g);
#pragma unroll
    for (int pb = 0; pb < 4; pb++) {
      f32x4 aE = MFMA(fE, xb[pb], bE, 0, 0, 0);
      f32x4 aO = MFMA(fO, xb[pb], bO, 0, 0, 0);
      h1[pb][obp] = pack8(leaky4(aE), leaky4(aO));
    }
  }
  __syncthreads();  // weight-stream alignment only

  // ---- L2: 64->128 (KS=2, 8 obs) ------------------------------------------
  const unsigned short* w2b = wb + OW2;
  bf16x8 h2[4][4];
#pragma unroll
  for (int obp = 0; obp < 4; obp++) {
    bf16x8 fE0, fE1, fO0, fO1;
    LDA(fE0, w2b, W2f, 64, 2, true, 2 * obp, 0);
    LDA(fE1, w2b, W2f, 64, 2, true, 2 * obp, 1);
    LDA(fO0, w2b, W2f, 64, 2, true, 2 * obp + 1, 0);
    LDA(fO1, w2b, W2f, 64, 2, true, 2 * obp + 1, 1);
    f32x4 bE = *(const f32x4*)(b2 + 32 * obp + 4 * g);
    f32x4 bO = *(const f32x4*)(b2 + 32 * obp + 16 + 4 * g);
#pragma unroll
    for (int pb = 0; pb < 4; pb++) {
      f32x4 aE = MFMA(fE0, h1[pb][0], bE, 0, 0, 0);
      aE = MFMA(fE1, h1[pb][1], aE, 0, 0, 0);
      f32x4 aO = MFMA(fO0, h1[pb][0], bO, 0, 0, 0);
      aO = MFMA(fO1, h1[pb][1], aO, 0, 0, 0);
      h2[pb][obp] = pack8(leaky4(aE), leaky4(aO));
    }
  }
  __syncthreads();

  // ---- L3: 128->256 (KS=4, 16 obs) ----------------------------------------
  const unsigned short* w3b = wb + OW3;
  bf16x8 h3[4][8];
#pragma unroll
  for (int obp = 0; obp < 8; obp++) {
    bf16x8 fE[4], fO[4];
#pragma unroll
    for (int ks = 0; ks < 4; ks++) {
      LDA(fE[ks], w3b, W3f, 128, 4, true, 2 * obp, ks);
      LDA(fO[ks], w3b, W3f, 128, 4, true, 2 * obp + 1, ks);
    }
    f32x4 bE = *(const f32x4*)(b3 + 32 * obp + 4 * g);
    f32x4 bO = *(const f32x4*)(b3 + 32 * obp + 16 + 4 * g);
#pragma unroll
    for (int pb = 0; pb < 4; pb++) {
      f32x4 aE = MFMA(fE[0], h2[pb][0], bE, 0, 0, 0);
      f32x4 aO = MFMA(fO[0], h2[pb][0], bO, 0, 0, 0);
#pragma unroll
      for (int ks = 1; ks < 4; ks++) {
        aE = MFMA(fE[ks], h2[pb][ks], aE, 0, 0, 0);
        aO = MFMA(fO[ks], h2[pb][ks], aO, 0, 0, 0);
      }
      h3[pb][obp] = pack8(leaky4(aE), leaky4(aO));
    }
  }
  __syncthreads();

  // ---- L4+L5 fused: 256->512->1 (KS=8, 32 obs, runtime loop) --------------
  const unsigned short* w4b = wb + OW4;
  f32x4 zp[4];
#pragma unroll
  for (int pb = 0; pb < 4; pb++) zp[pb] = f32x4{0.f, 0.f, 0.f, 0.f};

  for (int ob = 0; ob < 32; ob++) {
    bf16x8 f4[8];
#pragma unroll
    for (int ks = 0; ks < 8; ks++) LDA(f4[ks], w4b, W4f, 256, 8, true, ob, ks);
    f32x4 bv = *(const f32x4*)(b4 + 16 * ob + 4 * g);
    f32x4 w5v = *(const f32x4*)(W5f + 16 * ob + 4 * g);
#pragma unroll
    for (int pb = 0; pb < 4; pb++) {
      f32x4 a = MFMA(f4[0], h3[pb][0], bv, 0, 0, 0);
#pragma unroll
      for (int ks = 1; ks < 8; ks++) a = MFMA(f4[ks], h3[pb][ks], a, 0, 0, 0);
      f32x4 lv = leaky4(a);
#pragma unroll
      for (int i = 0; i < 4; i++) zp[pb][i] = fmaf(lv[i], w5v[i], zp[pb][i]);
    }
  }

  // ---- z per pixel + BCE + reduction --------------------------------------
  float zb[4];
#pragma unroll
  for (int pb = 0; pb < 4; pb++) {
    float s = zp[pb][0] + zp[pb][1] + zp[pb][2] + zp[pb][3];
    s += __shfl_xor(s, 16);
    s += __shfl_xor(s, 32);
    zb[pb] = s;  // full z for px (pb,li), replicated across g
  }
  float zsel = (g == 0) ? zb[0] : (g == 1) ? zb[1] : (g == 2) ? zb[2] : zb[3];
  float z = zsel + b5[0];
  float lab = lbl[px0 + lane];
  float w = fmaxf(z, 0.f) - z * lab + log1pf(expf(-fabsf(z)));
#pragma unroll
  for (int m = 1; m <= 32; m <<= 1) w += __shfl_xor(w, m);
  if (lane == 0) zs[wave] = w;
  __syncthreads();
  if (t == 0)
    atomicAdd(out, (zs[0] + zs[1] + zs[2] + zs[3]) * (1.f / (float)NPIX));
}

extern "C" void kernel_launch(void* const* d_in, const int* in_sizes, int n_in,
                              void* d_out, int out_size, void* d_ws, size_t ws_size,
                              hipStream_t stream) {
  const float* x   = (const float*)d_in[0];
  const float* lbl = (const float*)d_in[1];
  const float* W1  = (const float*)d_in[2];
  const float* b1  = (const float*)d_in[3];
  const float* W2  = (const float*)d_in[4];
  const float* b2  = (const float*)d_in[5];
  const float* W3  = (const float*)d_in[6];
  const float* b3  = (const float*)d_in[7];
  const float* W4  = (const float*)d_in[8];
  const float* b4  = (const float*)d_in[9];
  const float* W5  = (const float*)d_in[10];
  const float* b5  = (const float*)d_in[11];
  float* out = (float*)d_out;

  hipMemsetAsync(d_out, 0, sizeof(float), stream);

  bool pre = ws_size >= (size_t)WTOT * sizeof(unsigned short);
  if (pre) {
    unsigned short* wbp = (unsigned short*)d_ws;
    wconv_kernel<<<(WTOT + 255) / 256, 256, 0, stream>>>(W1, W2, W3, W4, wbp);
    disc_main<true><<<NPIX / 256, 256, 0, stream>>>(x, lbl, wbp, W1, b1, W2, b2, W3, b3,
                                                    W4, b4, W5, b5, out);
  } else {
    disc_main<false><<<NPIX / 256, 256, 0, stream>>>(x, lbl, nullptr, W1, b1, W2, b2,
                                                     W3, b3, W4, b4, W5, b5, out);
  }
}

// Round 5
// 285.313 us; speedup vs baseline: 1.0664x; 1.0664x over previous
//
#include <hip/hip_runtime.h>

// get_fc_pix_discriminator_1x1_solo: fused 5-layer per-pixel MLP + BCE mean.
// B=4, C=19, H=256, W=512 -> 524288 px. dims 19->64->128->256->512->1.
// R5: same fully-register-resident structure as R4, but __launch_bounds__
// (256,1): R4's (256,2) produced a 128-VGPR allocation vs a ~250-reg live set
// at the L3->L4 boundary -> 340MB/dispatch scratch spill (FETCH 132MB, WRITE
// 211MB). At 1 wave/SIMD the live set fits (cap 512); 4-way pb MFMA ILP +
// deep-pipelined weight-frag loads hide latency from within the wave.

#define HW_ 131072      // 256*512 = 2^17
#define NPIX 524288

using bf16x8 = __attribute__((ext_vector_type(8))) short;
using f32x4  = __attribute__((ext_vector_type(4))) float;

#define MFMA __builtin_amdgcn_mfma_f32_16x16x32_bf16

__device__ __forceinline__ unsigned short f2bf(float f) {
  unsigned u = __builtin_bit_cast(unsigned, f);
  u += 0x7FFFu + ((u >> 16) & 1u);   // round-to-nearest-even
  return (unsigned short)(u >> 16);
}

// sigma^-1: k-slot -> source feature index (within 32-chunks)
__device__ __forceinline__ int kinv(int k) {
  return ((k >> 5) << 5) + (((k >> 2) & 1) << 4) + (((k >> 3) & 3) << 2) + (k & 3);
}

// ---- weight bf16 pre-conversion into MFMA A-fragment order ----------------
// layer frag space: [ob = out-block 0..N/16)][ks = 0..KP/32)][lane][j 0..8)
//   o = ob*16 + (lane&15),  k = ks*32 + (lane>>4)*8 + j,
//   feature f = PERM ? kinv(k) : k   (zero if f >= K0)
// elem offset = ((ob*KS+ks)<<9) + lane*8. One wave A-frag load = 1KB coalesced.
#define OW1 0
#define OW2 2048
#define OW3 10240
#define OW4 43008
#define WTOT 174080

template <int K0, int KP, bool PERM>
__device__ __forceinline__ void conv_layer(const float* __restrict__ W,
                                           unsigned short* __restrict__ out,
                                           int i) {
  int r9 = i & 511;
  int lane = r9 >> 3, j = r9 & 7;
  int frag = i >> 9;               // = ob*KS + ks
  constexpr int KS = KP / 32;
  int ob = frag / KS, ks = frag - ob * KS;
  int o = ob * 16 + (lane & 15);
  int k = ks * 32 + ((lane >> 4) << 3) + j;
  int f = PERM ? kinv(k) : k;
  out[i] = f2bf(f < K0 ? W[o * K0 + f] : 0.f);
}

__global__ void wconv_kernel(const float* __restrict__ W1, const float* __restrict__ W2,
                             const float* __restrict__ W3, const float* __restrict__ W4,
                             unsigned short* __restrict__ wb) {
  int i = blockIdx.x * 256 + threadIdx.x;
  if (i < OW2) {
    conv_layer<19, 32, false>(W1, wb + OW1, i - OW1);
  } else if (i < OW3) {
    conv_layer<64, 64, true>(W2, wb + OW2, i - OW2);
  } else if (i < OW4) {
    conv_layer<128, 128, true>(W3, wb + OW3, i - OW3);
  } else if (i < WTOT) {
    conv_layer<256, 256, true>(W4, wb + OW4, i - OW4);
  }
}

__device__ __forceinline__ f32x4 leaky4(f32x4 v) {
  f32x4 r;
#pragma unroll
  for (int i = 0; i < 4; i++) r[i] = fmaxf(v[i], 0.2f * v[i]);
  return r;
}
__device__ __forceinline__ bf16x8 pack8(f32x4 e, f32x4 o) {
  bf16x8 r;
#pragma unroll
  for (int i = 0; i < 4; i++) {
    r[i] = (short)f2bf(e[i]);
    r[4 + i] = (short)f2bf(o[i]);
  }
  return r;
}

// A-frag load: PRE -> 16B vector load from frag-ordered wb; else scalar gather
#define LDA(dst, wbase, Wf, K0, KS, PERM, ob, ks)                              \
  do {                                                                         \
    if constexpr (PRE) {                                                       \
      dst = *(const bf16x8*)((wbase) + ((((ob) * (KS) + (ks)) << 9) + (lane << 3))); \
    } else {                                                                   \
      int o_ = (ob) * 16 + li;                                                 \
      for (int j_ = 0; j_ < 8; j_++) {                                         \
        int k_ = (ks) * 32 + (g << 3) + j_;                                    \
        int f_ = (PERM) ? kinv(k_) : k_;                                       \
        float v_ = f_ < (K0) ? (Wf)[o_ * (K0) + f_] : 0.f;                     \
        dst[j_] = (short)f2bf(v_);                                             \
      }                                                                        \
    }                                                                          \
  } while (0)

template <bool PRE>
__global__ __launch_bounds__(256, 1) void disc_main(
    const float* __restrict__ x, const float* __restrict__ lbl,
    const unsigned short* __restrict__ wb,
    const float* __restrict__ W1f, const float* __restrict__ b1,
    const float* __restrict__ W2f, const float* __restrict__ b2,
    const float* __restrict__ W3f, const float* __restrict__ b3,
    const float* __restrict__ W4f, const float* __restrict__ b4,
    const float* __restrict__ W5f, const float* __restrict__ b5,
    float* __restrict__ out) {
  __shared__ float zs[4];

  int t = threadIdx.x;
  int wave = t >> 6, lane = t & 63;
  int g = lane >> 4, li = lane & 15;
  long px0 = ((long)blockIdx.x * 4 + wave) * 64;
  int b = (int)(px0 >> 17);
  int hw0 = (int)(px0 & (HW_ - 1));

  // ---- x -> B-frags (k = input channel c, natural order; c>=19 zero) ------
  bf16x8 xb[4];
#pragma unroll
  for (int pb = 0; pb < 4; pb++) {
    const float* xp = x + (((long)b * 19) << 17) + hw0 + pb * 16 + li;
    bf16x8 v;
#pragma unroll
    for (int j = 0; j < 8; j++) {
      int c = 8 * g + j;
      float f = (c < 19) ? xp[(long)c << 17] : 0.f;
      v[j] = (short)f2bf(f);
    }
    xb[pb] = v;
  }

  // ---- L1: 19->64 (KS=1, 4 obs) -------------------------------------------
  const unsigned short* w1b = wb + OW1;
  bf16x8 h1[4][2];
#pragma unroll
  for (int obp = 0; obp < 2; obp++) {
    bf16x8 fE, fO;
    LDA(fE, w1b, W1f, 19, 1, false, 2 * obp, 0);
    LDA(fO, w1b, W1f, 19, 1, false, 2 * obp + 1, 0);
    f32x4 bE = *(const f32x4*)(b1 + 32 * obp + 4 * g);
    f32x4 bO = *(const f32x4*)(b1 + 32 * obp + 16 + 4 * g);
#pragma unroll
    for (int pb = 0; pb < 4; pb++) {
      f32x4 aE = MFMA(fE, xb[pb], bE, 0, 0, 0);
      f32x4 aO = MFMA(fO, xb[pb], bO, 0, 0, 0);
      h1[pb][obp] = pack8(leaky4(aE), leaky4(aO));
    }
  }
  __syncthreads();  // weight-stream alignment only

  // ---- L2: 64->128 (KS=2, 8 obs) ------------------------------------------
  const unsigned short* w2b = wb + OW2;
  bf16x8 h2[4][4];
#pragma unroll
  for (int obp = 0; obp < 4; obp++) {
    bf16x8 fE0, fE1, fO0, fO1;
    LDA(fE0, w2b, W2f, 64, 2, true, 2 * obp, 0);
    LDA(fE1, w2b, W2f, 64, 2, true, 2 * obp, 1);
    LDA(fO0, w2b, W2f, 64, 2, true, 2 * obp + 1, 0);
    LDA(fO1, w2b, W2f, 64, 2, true, 2 * obp + 1, 1);
    f32x4 bE = *(const f32x4*)(b2 + 32 * obp + 4 * g);
    f32x4 bO = *(const f32x4*)(b2 + 32 * obp + 16 + 4 * g);
#pragma unroll
    for (int pb = 0; pb < 4; pb++) {
      f32x4 aE = MFMA(fE0, h1[pb][0], bE, 0, 0, 0);
      aE = MFMA(fE1, h1[pb][1], aE, 0, 0, 0);
      f32x4 aO = MFMA(fO0, h1[pb][0], bO, 0, 0, 0);
      aO = MFMA(fO1, h1[pb][1], aO, 0, 0, 0);
      h2[pb][obp] = pack8(leaky4(aE), leaky4(aO));
    }
  }
  __syncthreads();

  // ---- L3: 128->256 (KS=4, 16 obs) ----------------------------------------
  const unsigned short* w3b = wb + OW3;
  bf16x8 h3[4][8];
#pragma unroll
  for (int obp = 0; obp < 8; obp++) {
    bf16x8 fE[4], fO[4];
#pragma unroll
    for (int ks = 0; ks < 4; ks++) {
      LDA(fE[ks], w3b, W3f, 128, 4, true, 2 * obp, ks);
      LDA(fO[ks], w3b, W3f, 128, 4, true, 2 * obp + 1, ks);
    }
    f32x4 bE = *(const f32x4*)(b3 + 32 * obp + 4 * g);
    f32x4 bO = *(const f32x4*)(b3 + 32 * obp + 16 + 4 * g);
#pragma unroll
    for (int pb = 0; pb < 4; pb++) {
      f32x4 aE = MFMA(fE[0], h2[pb][0], bE, 0, 0, 0);
      f32x4 aO = MFMA(fO[0], h2[pb][0], bO, 0, 0, 0);
#pragma unroll
      for (int ks = 1; ks < 4; ks++) {
        aE = MFMA(fE[ks], h2[pb][ks], aE, 0, 0, 0);
        aO = MFMA(fO[ks], h2[pb][ks], aO, 0, 0, 0);
      }
      h3[pb][obp] = pack8(leaky4(aE), leaky4(aO));
    }
  }
  __syncthreads();

  // ---- L4+L5 fused: 256->512->1 (KS=8, 32 obs, runtime loop) --------------
  const unsigned short* w4b = wb + OW4;
  f32x4 zp[4];
#pragma unroll
  for (int pb = 0; pb < 4; pb++) zp[pb] = f32x4{0.f, 0.f, 0.f, 0.f};

  for (int ob = 0; ob < 32; ob++) {
    bf16x8 f4[8];
#pragma unroll
    for (int ks = 0; ks < 8; ks++) LDA(f4[ks], w4b, W4f, 256, 8, true, ob, ks);
    f32x4 bv = *(const f32x4*)(b4 + 16 * ob + 4 * g);
    f32x4 w5v = *(const f32x4*)(W5f + 16 * ob + 4 * g);
#pragma unroll
    for (int pb = 0; pb < 4; pb++) {
      f32x4 a = MFMA(f4[0], h3[pb][0], bv, 0, 0, 0);
#pragma unroll
      for (int ks = 1; ks < 8; ks++) a = MFMA(f4[ks], h3[pb][ks], a, 0, 0, 0);
      f32x4 lv = leaky4(a);
#pragma unroll
      for (int i = 0; i < 4; i++) zp[pb][i] = fmaf(lv[i], w5v[i], zp[pb][i]);
    }
  }

  // ---- z per pixel + BCE + reduction --------------------------------------
  float zb[4];
#pragma unroll
  for (int pb = 0; pb < 4; pb++) {
    float s = zp[pb][0] + zp[pb][1] + zp[pb][2] + zp[pb][3];
    s += __shfl_xor(s, 16);
    s += __shfl_xor(s, 32);
    zb[pb] = s;  // full z for px (pb,li), replicated across g
  }
  float zsel = (g == 0) ? zb[0] : (g == 1) ? zb[1] : (g == 2) ? zb[2] : zb[3];
  float z = zsel + b5[0];
  float lab = lbl[px0 + lane];
  float w = fmaxf(z, 0.f) - z * lab + log1pf(expf(-fabsf(z)));
#pragma unroll
  for (int m = 1; m <= 32; m <<= 1) w += __shfl_xor(w, m);
  if (lane == 0) zs[wave] = w;
  __syncthreads();
  if (t == 0)
    atomicAdd(out, (zs[0] + zs[1] + zs[2] + zs[3]) * (1.f / (float)NPIX));
}

extern "C" void kernel_launch(void* const* d_in, const int* in_sizes, int n_in,
                              void* d_out, int out_size, void* d_ws, size_t ws_size,
                              hipStream_t stream) {
  const float* x   = (const float*)d_in[0];
  const float* lbl = (const float*)d_in[1];
  const float* W1  = (const float*)d_in[2];
  const float* b1  = (const float*)d_in[3];
  const float* W2  = (const float*)d_in[4];
  const float* b2  = (const float*)d_in[5];
  const float* W3  = (const float*)d_in[6];
  const float* b3  = (const float*)d_in[7];
  const float* W4  = (const float*)d_in[8];
  const float* b4  = (const float*)d_in[9];
  const float* W5  = (const float*)d_in[10];
  const float* b5  = (const float*)d_in[11];
  float* out = (float*)d_out;

  hipMemsetAsync(d_out, 0, sizeof(float), stream);

  bool pre = ws_size >= (size_t)WTOT * sizeof(unsigned short);
  if (pre) {
    unsigned short* wbp = (unsigned short*)d_ws;
    wconv_kernel<<<(WTOT + 255) / 256, 256, 0, stream>>>(W1, W2, W3, W4, wbp);
    disc_main<true><<<NPIX / 256, 256, 0, stream>>>(x, lbl, wbp, W1, b1, W2, b2, W3, b3,
                                                    W4, b4, W5, b5, out);
  } else {
    disc_main<false><<<NPIX / 256, 256, 0, stream>>>(x, lbl, nullptr, W1, b1, W2, b2,
                                                     W3, b3, W4, b4, W5, b5, out);
  }
}